// Round 6
// baseline (1109.767 us; speedup 1.0000x reference)
//
#include <hip/hip_runtime.h>
#include <math.h>

// Problem constants
#define Bb   64
#define Cc   100
#define Ff   2048
#define Tt   32
#define Hh   300
#define N4P  1216   // 4 gates * H padded to 19*64, interleaved n = 4*col + gate
#define KH   304    // H padded to 19*16
#define NPP  336    // 300 padded to 7*48
#define KOP  304    // 300 padded to 19*16
#define NH   624    // 2*H padded to 13*48 (h0/c0 interleaved n = 2*col + g)
#define BOSi 1
#define NWG  75     // recurrence workgroups (75 * 4 hcols = 300)

__device__ __forceinline__ float sigmf_(float x){ return 1.0f/(1.0f + expf(-x)); }

__device__ __forceinline__ void fma16_(const float4 av, const float4 bv, float acc[4][4]){
    acc[0][0] += av.x*bv.x; acc[0][1] += av.x*bv.y; acc[0][2] += av.x*bv.z; acc[0][3] += av.x*bv.w;
    acc[1][0] += av.y*bv.x; acc[1][1] += av.y*bv.y; acc[1][2] += av.y*bv.z; acc[1][3] += av.y*bv.w;
    acc[2][0] += av.z*bv.x; acc[2][1] += av.z*bv.y; acc[2][2] += av.z*bv.z; acc[2][3] += av.z*bv.w;
    acc[3][0] += av.w*bv.x; acc[3][1] += av.w*bv.y; acc[3][2] += av.w*bv.z; acc[3][3] += av.w*bv.w;
}

// ---------------------------------------------------------------------------
// Pack: W4e_p [KH][N4P] (comb rows 0..299), W4h_p [KH][N4P] (rows 300..599),
// W4c_p [2048][N4P] (rows 600..2647), Whc_p [2048][NH] (Wh0/Wc0 interleaved),
// b4p, pb_b = bcp+bhp, bhc, flags reset.   All gate-interleaved n = 4*col+g.
// ---------------------------------------------------------------------------
__global__ void k_pack(const float* Wi, const float* Wf, const float* Wo, const float* Wg,
                       const float* bi, const float* bf, const float* bo, const float* bg,
                       const float* bcp, const float* bhp,
                       const float* bh0, const float* bc0,
                       const float* Wh0, const float* Wc0,
                       float* W4e_p, float* W4h_p, float* W4c_p, float* Whc_p,
                       float* b4p, float* pb_b, float* bhc, int* flags)
{
    const int total = 2*KH*N4P + 2048*N4P + 2048*NH + N4P + NPP + NH + 128;
    for (int idx = blockIdx.x*256 + threadIdx.x; idx < total; idx += gridDim.x*256) {
        int i = idx;
        if (i < KH*N4P) {
            int k = i / N4P, n = i % N4P, c = n >> 2, g = n & 3;
            const float* W = (g==0)?Wi:(g==1)?Wf:(g==2)?Wo:Wg;
            W4e_p[i] = (k < Hh && c < Hh) ? W[k*Hh + c] : 0.0f;
            continue;
        }
        i -= KH*N4P;
        if (i < KH*N4P) {
            int k = i / N4P, n = i % N4P, c = n >> 2, g = n & 3;
            const float* W = (g==0)?Wi:(g==1)?Wf:(g==2)?Wo:Wg;
            W4h_p[i] = (k < Hh && c < Hh) ? W[(Hh + k)*Hh + c] : 0.0f;
            continue;
        }
        i -= KH*N4P;
        if (i < 2048*N4P) {
            int k = i / N4P, n = i % N4P, c = n >> 2, g = n & 3;
            const float* W = (g==0)?Wi:(g==1)?Wf:(g==2)?Wo:Wg;
            W4c_p[i] = (c < Hh) ? W[(2*Hh + k)*Hh + c] : 0.0f;
            continue;
        }
        i -= 2048*N4P;
        if (i < 2048*NH) {
            int k = i / NH, n = i % NH, c = n >> 1, g = n & 1;
            Whc_p[i] = (c < Hh) ? (g ? Wc0[k*Hh + c] : Wh0[k*Hh + c]) : 0.0f;
            continue;
        }
        i -= 2048*NH;
        if (i < N4P) {
            int c = i >> 2, g = i & 3;
            const float* bb = (g==0)?bi:(g==1)?bf:(g==2)?bo:bg;
            b4p[i] = (c < Hh) ? bb[c] : 0.0f;
            continue;
        }
        i -= N4P;
        if (i < NPP) {
            pb_b[i] = (i < Hh) ? (bcp[i] + bhp[i]) : 0.0f;
            continue;
        }
        i -= NPP;
        if (i < NH) {
            int c = i >> 1, g = i & 1;
            bhc[i] = (c < Hh) ? (g ? bc0[c] : bh0[c]) : 0.0f;
            continue;
        }
        i -= NH;
        flags[i] = (i < NWG) ? 0 : 0x7fffffff;   // reset every launch
    }
}

// ---------------------------------------------------------------------------
// meanT[f][b] = mean over channels. grid (8 f-tiles, 64 b), 256 thr.
// ---------------------------------------------------------------------------
__global__ __launch_bounds__(256) void k_meanT(const float* enc, float* meanT)
{
    const int b = blockIdx.y, f = blockIdx.x*256 + threadIdx.x;
    const float* pe = enc + (b*Cc)*Ff + f;
    float s = 0.0f;
#pragma unroll 10
    for (int c = 0; c < Cc; c++) s += pe[c*Ff];
    meanT[f*64 + b] = s * (1.0f/Cc);
}

// e_enc[b][c] = dot(enc[b,c,:], We_enc). grid (25 c-groups, 64 b), wave per c.
__global__ __launch_bounds__(256) void k_eenc(const float* enc, const float* We_enc, float* e_enc)
{
    const int b = blockIdx.y;
    const int w = threadIdx.x >> 6, lane = threadIdx.x & 63;
    const int c = blockIdx.x*4 + w;
    if (c < Cc) {
        const float* p = enc + (b*Cc + c)*Ff;
        float s = 0.0f;
        for (int k = lane; k < Ff; k += 64) s += p[k]*We_enc[k];
        for (int o = 32; o; o >>= 1) s += __shfl_xor(s, o);
        if (lane == 0) e_enc[b*Cc + c] = s;
    }
}

// ctx[f][b] = sum_c softmax(e_enc[b,:])[c]*enc[b][c][f] -- ONCE.
// (h-term of the energy is constant over c => softmax is time-invariant.)
__global__ __launch_bounds__(256) void k_ctx(const float* enc, const float* e_enc, float* ctxT)
{
    const int b = blockIdx.y, f = blockIdx.x*256 + threadIdx.x;
    __shared__ float sA[128];
    if (threadIdx.x < 64) {
        const int lane = threadIdx.x;
        float v0 = e_enc[b*Cc + lane];
        float v1 = (lane + 64 < Cc) ? e_enc[b*Cc + lane + 64] : -1e30f;
        float m = fmaxf(v0, v1);
        for (int o = 32; o; o >>= 1) m = fmaxf(m, __shfl_xor(m, o));
        float e0 = expf(v0 - m);
        float e1 = (lane + 64 < Cc) ? expf(v1 - m) : 0.0f;
        float s = e0 + e1;
        for (int o = 32; o; o >>= 1) s += __shfl_xor(s, o);
        float inv = 1.0f / s;
        sA[lane] = e0 * inv;
        sA[lane + 64] = e1 * inv;
    }
    __syncthreads();
    const float* pe = enc + (b*Cc)*Ff + f;
    float acc = 0.0f;
#pragma unroll 10
    for (int c = 0; c < Cc; c++) acc += sA[c] * pe[c*Ff];
    ctxT[f*64 + b] = acc;
}

// Embedding gather E[t][j][b] + BOS row of out (merged).
__global__ void k_embed(const int* caps, const float* emb, float* E, float* out)
{
    const int idx = blockIdx.x*256 + threadIdx.x;
    const int nE = (Tt-1)*Hh*Bb;
    if (idx < nE) {
        const int j = idx % Hh;
        const int bt = idx / Hh;
        const int b = bt / (Tt-1), t = bt % (Tt-1);
        E[(t*Hh + j)*64 + b] = emb[(long)caps[b*Tt + t]*Hh + j];
    } else {
        const int r = idx - nE;
        if (r < Bb*Hh) {
            const int b = r / Hh, j = r % Hh;
            out[(b*Tt)*Hh + j] = emb[(long)BOSi*Hh + j];
        }
    }
}

// ---------------------------------------------------------------------------
// h0/c0 GEMM: meanT (64 x 2048) @ Whc_p (2048 x 624, packed). grid (13, 8).
// ---------------------------------------------------------------------------
__global__ __launch_bounds__(192) void k_gemm_h0(const float* meanT,
                                                 const float* Whc_p,
                                                 float* parth)
{
    const int nt = blockIdx.x, ks = blockIdx.y, tid = threadIdx.x;
    const int n0 = nt*48, tx = tid % 12, ty = tid / 12;
    __shared__ float As[16][64];
    __shared__ float Bs[16][48];
    float acc[4][4] = {};
    const int k0 = ks*256;
    for (int kb = 0; kb < 16; kb++) {
        const int kbase = k0 + kb*16;
        for (int idx = tid; idx < 1024; idx += 192) {
            int kk = idx >> 6, bb = idx & 63;
            As[kk][bb] = meanT[(kbase + kk)*64 + bb];
        }
        for (int idx = tid; idx < 768; idx += 192) {
            int kk = idx / 48, nn = idx % 48;
            Bs[kk][nn] = Whc_p[(kbase + kk)*NH + n0 + nn];
        }
        __syncthreads();
#pragma unroll
        for (int kk = 0; kk < 16; kk++) {
            float4 av = *(const float4*)&As[kk][ty*4];
            float4 bv = *(const float4*)&Bs[kk][tx*4];
            fma16_(av, bv, acc);
        }
        __syncthreads();
    }
#pragma unroll
    for (int i = 0; i < 4; i++)
        *(float4*)&parth[(ks*64 + ty*4 + i)*NH + n0 + tx*4]
            = make_float4(acc[i][0], acc[i][1], acc[i][2], acc[i][3]);
}

// h0/c0 epilogue. grid 64 (b), 256 thr.
__global__ __launch_bounds__(256) void k_h0fin2(const float* parth, const float* bhc,
                                                float* hT, float* c0T)
{
    const int b = blockIdx.x, tid = threadIdx.x;
    for (int col = tid; col < Hh; col += 256) {
        float sh = bhc[2*col], sc = bhc[2*col+1];
        for (int ks = 0; ks < 8; ks++) {
            const float2 v = *(const float2*)&parth[(ks*64 + b)*NH + 2*col];
            sh += v.x; sc += v.y;
        }
        hT[(0*Hh + col)*64 + b] = tanhf(sh);
        c0T[col*64 + b] = tanhf(sc);
    }
}

// ---------------------------------------------------------------------------
// C partials: ctx (64x2048) @ W4c_p (2048x1216, packed). grid (19, 8), 256 thr.
// Output partC[ks][n][b].
// ---------------------------------------------------------------------------
__global__ __launch_bounds__(256) void k_gemm_C(const float* ctxT,
                                                const float* W4c_p,
                                                float* partC)
{
    const int nt = blockIdx.x, ks = blockIdx.y, tid = threadIdx.x;
    const int n0 = nt*64, tx = tid & 15, ty = tid >> 4;
    __shared__ float As[16][64];
    __shared__ float Bs[16][64];
    float acc[4][4] = {};
    const int k0 = ks*256;
    for (int kb = 0; kb < 16; kb++) {
        const int kbase = k0 + kb*16;
#pragma unroll
        for (int i = 0; i < 4; i++) {
            int idx = tid + i*256;
            int kk = idx >> 6, bb = idx & 63;
            As[kk][bb] = ctxT[(kbase + kk)*64 + bb];
        }
#pragma unroll
        for (int i = 0; i < 4; i++) {
            int idx = tid + i*256;
            int kk = idx >> 6, nn = idx & 63;
            Bs[kk][nn] = W4c_p[(kbase + kk)*N4P + n0 + nn];
        }
        __syncthreads();
#pragma unroll
        for (int kk = 0; kk < 16; kk++) {
            float4 av = *(const float4*)&As[kk][ty*4];
            float4 bv = *(const float4*)&Bs[kk][tx*4];
            fma16_(av, bv, acc);
        }
        __syncthreads();
    }
#pragma unroll
    for (int jn = 0; jn < 4; jn++) {
        float4 v = make_float4(acc[0][jn], acc[1][jn], acc[2][jn], acc[3][jn]);
        *(float4*)&partC[((ks*N4P) + n0 + tx*4 + jn)*64 + ty*4] = v;
    }
}

// ---------------------------------------------------------------------------
// gpre[t][n][b] = (E_t @ W4e_p)[n][b] + sum_ks partC[ks][n][b] + b4p[n].
// grid (19 nt, 31 t), 256 thr.
// ---------------------------------------------------------------------------
__global__ __launch_bounds__(256) void k_gemm_gpre(const float* E,
                                                   const float* W4e_p,
                                                   const float* partC, const float* b4p,
                                                   float* gpre)
{
    const int nt = blockIdx.x, t = blockIdx.y, tid = threadIdx.x;
    const int n0 = nt*64, tx = tid & 15, ty = tid >> 4;
    __shared__ float As[16][64];
    __shared__ float Bs[16][64];
    float acc[4][4] = {};
    for (int kb = 0; kb < 19; kb++) {
        const int kbase = kb*16;
#pragma unroll
        for (int i = 0; i < 4; i++) {
            int idx = tid + i*256;
            int kk = idx >> 6, bb = idx & 63, j = kbase + kk;
            As[kk][bb] = (j < Hh) ? E[(t*Hh + j)*64 + bb] : 0.0f;
        }
#pragma unroll
        for (int i = 0; i < 4; i++) {
            int idx = tid + i*256;
            int kk = idx >> 6, nn = idx & 63;
            Bs[kk][nn] = W4e_p[(kbase + kk)*N4P + n0 + nn];
        }
        __syncthreads();
#pragma unroll
        for (int kk = 0; kk < 16; kk++) {
            float4 av = *(const float4*)&As[kk][ty*4];
            float4 bv = *(const float4*)&Bs[kk][tx*4];
            fma16_(av, bv, acc);
        }
        __syncthreads();
    }
#pragma unroll
    for (int jn = 0; jn < 4; jn++) {
        const int n = n0 + tx*4 + jn;
        float4 ps = make_float4(0,0,0,0);
        for (int ks = 0; ks < 8; ks++) {
            const float4 v = *(const float4*)&partC[(ks*N4P + n)*64 + ty*4];
            ps.x += v.x; ps.y += v.y; ps.z += v.z; ps.w += v.w;
        }
        const float bv = b4p[n];
        float4 o;
        o.x = acc[0][jn] + ps.x + bv;
        o.y = acc[1][jn] + ps.y + bv;
        o.z = acc[2][jn] + ps.z + bv;
        o.w = acc[3][jn] + ps.w + bv;
        *(float4*)&gpre[((long)t*N4P + n)*64 + ty*4] = o;
    }
}

// ---------------------------------------------------------------------------
// pbias partials: ctx @ Wcp. grid (7, 8), 192 thr. Output ppb[ks][n][b].
// ---------------------------------------------------------------------------
__global__ __launch_bounds__(192) void k_gemm_pb(const float* ctxT, const float* Wcp,
                                                 float* ppb)
{
    const int nt = blockIdx.x, ks = blockIdx.y, tid = threadIdx.x;
    const int n0 = nt*48, tx = tid % 12, ty = tid / 12;
    __shared__ float As[16][64];
    __shared__ float Bs[16][48];
    float acc[4][4] = {};
    const int k0 = ks*256;
    for (int kb = 0; kb < 16; kb++) {
        const int kbase = k0 + kb*16;
        for (int idx = tid; idx < 1024; idx += 192) {
            int kk = idx >> 6, bb = idx & 63;
            As[kk][bb] = ctxT[(kbase + kk)*64 + bb];
        }
        for (int idx = tid; idx < 768; idx += 192) {
            int kk = idx / 48, nn = idx % 48, n = n0 + nn;
            Bs[kk][nn] = (n < Hh) ? Wcp[(kbase + kk)*Hh + n] : 0.0f;
        }
        __syncthreads();
#pragma unroll
        for (int kk = 0; kk < 16; kk++) {
            float4 av = *(const float4*)&As[kk][ty*4];
            float4 bv = *(const float4*)&Bs[kk][tx*4];
            fma16_(av, bv, acc);
        }
        __syncthreads();
    }
#pragma unroll
    for (int jn = 0; jn < 4; jn++) {
        float4 v = make_float4(acc[0][jn], acc[1][jn], acc[2][jn], acc[3][jn]);
        *(float4*)&ppb[((ks*NPP) + n0 + tx*4 + jn)*64 + ty*4] = v;
    }
}

// ---------------------------------------------------------------------------
// Recurrence, flag-synced (no grid.sync), h STAGED IN LDS each step.
// 75 WGs x 512 thr (cooperative: co-residency). WG s owns h-cols [4s,4s+4)
// = 16 gate cols. Waves: hl = w&1 (8-gate-col group), kc = w>>1 (k-chunk of 75).
// Per step: poll flags -> stage h[t-1] (38 indep agent loads/thread -> LDS)
// -> GEMV from LDS (h rows 256B/instr, weights broadcast) -> psum reduce ->
// kc==0 computes gates/c/h for 2 hcols -> agent store -> flag.
// ---------------------------------------------------------------------------
__global__ __launch_bounds__(512) void k_recs(const float* __restrict__ W4h_p,
                                              const float* __restrict__ gpre,
                                              const float* __restrict__ c0T,
                                              float* __restrict__ hT,
                                              int* __restrict__ flags)
{
    const int s = blockIdx.x, tid = threadIdx.x;
    const int b = tid & 63, w = tid >> 6;
    const int hl = w & 1;        // which 8-gate-col half
    const int kc = w >> 1;       // k-chunk 0..3 (75 k each)
    __shared__ float wlds[300][16];      // weight slice [k][16 cols]
    __shared__ float hlds[300*64];       // h[t-1] staged, [k][b]
    __shared__ float psum[3][2][8][64];  // kc=1..3 partials

    for (int i = tid; i < 300*16; i += 512)
        wlds[i >> 4][i & 15] = W4h_p[(i >> 4)*N4P + 16*s + (i & 15)];

    float cs0 = 0.f, cs1 = 0.f;
    if (kc == 0) {
        const int hc = 4*s + 2*hl;
        cs0 = c0T[(hc+0)*64 + b];
        cs1 = c0T[(hc+1)*64 + b];
    }
    __syncthreads();

    const int k0 = kc*75;

    for (int t = 1; t < Tt; t++) {
        // gpre prefetch (kc==0 threads own the outputs)
        float gpv[8];
        if (kc == 0) {
            const float* gp = gpre + ((long)(t-1)*N4P + 16*s + 8*hl)*64 + b;
#pragma unroll
            for (int j = 0; j < 8; j++) gpv[j] = gp[j*64];
        }
        // wait for all WGs to have produced h[t-1]
        if (t >= 2) {
            if (tid < 64) {
                for (;;) {
                    const int v0 = __hip_atomic_load(&flags[tid], __ATOMIC_RELAXED,
                                                     __HIP_MEMORY_SCOPE_AGENT);
                    const int v1 = __hip_atomic_load(&flags[tid+64], __ATOMIC_RELAXED,
                                                     __HIP_MEMORY_SCOPE_AGENT);
                    if (__all(v0 >= t-1 && v1 >= t-1)) break;
                    __builtin_amdgcn_s_sleep(1);
                }
            }
            __syncthreads();
        }
        // stage h[t-1]: 19200 floats, cache-bypassing, fully independent loads
        {
            const float* hsrc = hT + (long)(t-1)*(Hh*64);
#pragma unroll
            for (int j = 0; j < 38; j++) {
                const int i = tid + j*512;
                if (i < 19200)
                    hlds[i] = __hip_atomic_load(hsrc + i, __ATOMIC_RELAXED,
                                                __HIP_MEMORY_SCOPE_AGENT);
            }
        }
        __syncthreads();
        // GEMV quarter from LDS: 8 gate cols x 75 k
        float a[8] = {0,0,0,0,0,0,0,0};
        const float* hp = hlds + k0*64 + b;
        const float* wp = &wlds[k0][hl*8];
#pragma unroll 5
        for (int k = 0; k < 75; k++) {
            const float hv = hp[k*64];
            const float4 w0 = *(const float4*)(wp + k*16);
            const float4 w1 = *(const float4*)(wp + k*16 + 4);
            a[0] += hv*w0.x; a[1] += hv*w0.y; a[2] += hv*w0.z; a[3] += hv*w0.w;
            a[4] += hv*w1.x; a[5] += hv*w1.y; a[6] += hv*w1.z; a[7] += hv*w1.w;
        }
        if (kc > 0) {
#pragma unroll
            for (int j = 0; j < 8; j++) psum[kc-1][hl][j][b] = a[j];
        }
        __syncthreads();
        if (kc == 0) {
#pragma unroll
            for (int j = 0; j < 8; j++)
                a[j] += psum[0][hl][j][b] + psum[1][hl][j][b] + psum[2][hl][j][b] + gpv[j];
            const int hc = 4*s + 2*hl;
            {
                const float ig = sigmf_(a[0]), fg = sigmf_(a[1]), og = sigmf_(a[2]);
                const float gg = tanhf(a[3]);
                cs0 = fg*cs0 + ig*gg;
                const float h = og*tanhf(cs0);
                __hip_atomic_store(&hT[(long)t*(Hh*64) + (hc+0)*64 + b], h,
                                   __ATOMIC_RELAXED, __HIP_MEMORY_SCOPE_AGENT);
            }
            {
                const float ig = sigmf_(a[4]), fg = sigmf_(a[5]), og = sigmf_(a[6]);
                const float gg = tanhf(a[7]);
                cs1 = fg*cs1 + ig*gg;
                const float h = og*tanhf(cs1);
                __hip_atomic_store(&hT[(long)t*(Hh*64) + (hc+1)*64 + b], h,
                                   __ATOMIC_RELAXED, __HIP_MEMORY_SCOPE_AGENT);
            }
        }
        __syncthreads();   // drains h stores (vmcnt 0 before barrier)
        if (tid == 0 && t < Tt-1)
            __hip_atomic_store(&flags[s], t, __ATOMIC_RELAXED,
                               __HIP_MEMORY_SCOPE_AGENT);
    }
}

// ---------------------------------------------------------------------------
// tmp[t][j][b] = E[t][j][b] + (h_{t+1} @ Whp)[j][b] + pbias[j][b].
// grid (7 nt, 31 t), 192 thr.
// ---------------------------------------------------------------------------
__global__ __launch_bounds__(192) void k_gemm_tmp(const float* hT, const float* Whp,
                                                  const float* E, const float* ppb,
                                                  const float* pb_b, float* tmpT)
{
    const int nt = blockIdx.x, ti = blockIdx.y, tid = threadIdx.x;
    const int n0 = nt*48, tx = tid % 12, ty = tid / 12;
    __shared__ float As[16][64];
    __shared__ float Bs[16][48];
    float acc[4][4] = {};
    for (int kb = 0; kb < 19; kb++) {
        const int kbase = kb*16;
        for (int idx = tid; idx < 1024; idx += 192) {
            int kk = idx >> 6, bb = idx & 63, j = kbase + kk;
            As[kk][bb] = (j < Hh) ? hT[((ti+1)*Hh + j)*64 + bb] : 0.0f;
        }
        for (int idx = tid; idx < 768; idx += 192) {
            int kk = idx / 48, nn = idx % 48, j = kbase + kk, n = n0 + nn;
            Bs[kk][nn] = (j < Hh && n < Hh) ? Whp[j*Hh + n] : 0.0f;
        }
        __syncthreads();
#pragma unroll
        for (int kk = 0; kk < 16; kk++) {
            float4 av = *(const float4*)&As[kk][ty*4];
            float4 bv = *(const float4*)&Bs[kk][tx*4];
            fma16_(av, bv, acc);
        }
        __syncthreads();
    }
#pragma unroll
    for (int i = 0; i < 4; i++) {
        const int bb = ty*4 + i;
#pragma unroll
        for (int j = 0; j < 4; j++) {
            const int n = n0 + tx*4 + j;
            if (n < KOP) {
                float v = acc[i][j];
                if (n < Hh) {
                    float pb = pb_b[n];
                    for (int ks = 0; ks < 8; ks++) pb += ppb[(ks*NPP + n)*64 + bb];
                    v += E[(ti*Hh + n)*64 + bb] + pb;
                }
                tmpT[(ti*KOP + n)*64 + bb] = v;
            }
        }
    }
}

// Stage B: out[:, t+1, :] = tmp @ Wop + bop. grid (7, 31).
__global__ __launch_bounds__(192) void k_predb(const float* tmpT, const float* Wop,
                                               const float* bop, float* out)
{
    const int nt = blockIdx.x, ti = blockIdx.y, tid = threadIdx.x;
    const int n0 = nt*48, tx = tid % 12, ty = tid / 12;
    __shared__ float As[16][64];
    __shared__ float Bs[16][48];
    float acc[4][4] = {};
    const float* Asrc = tmpT + ti*KOP*64;

    for (int kb = 0; kb < 19; kb++) {
        const int kbase = kb*16;
        for (int idx = tid; idx < 1024; idx += 192) {
            int kk = idx >> 6, bb = idx & 63;
            As[kk][bb] = Asrc[(kbase + kk)*64 + bb];
        }
        for (int idx = tid; idx < 768; idx += 192) {
            int kk = idx / 48, nn = idx % 48, j = kbase + kk, n = n0 + nn;
            Bs[kk][nn] = (j < Hh && n < Hh) ? Wop[j*Hh + n] : 0.0f;
        }
        __syncthreads();
#pragma unroll
        for (int kk = 0; kk < 16; kk++) {
            float4 av = *(const float4*)&As[kk][ty*4];
            float4 bv = *(const float4*)&Bs[kk][tx*4];
            fma16_(av, bv, acc);
        }
        __syncthreads();
    }
#pragma unroll
    for (int i = 0; i < 4; i++) {
        const int bb = ty*4 + i;
#pragma unroll
        for (int j = 0; j < 4; j++) {
            const int n = n0 + tx*4 + j;
            if (n < Hh)
                out[(bb*Tt + (ti+1))*Hh + n] = acc[i][j] + bop[n];
        }
    }
}

// ---------------------------------------------------------------------------
extern "C" void kernel_launch(void* const* d_in, const int* in_sizes, int n_in,
                              void* d_out, int out_size, void* d_ws, size_t ws_size,
                              hipStream_t stream)
{
    const float* enc    = (const float*)d_in[0];
    const int*   caps   = (const int*)  d_in[1];
    const float* emb    = (const float*)d_in[2];
    const float* Wh0    = (const float*)d_in[3];
    const float* bh0    = (const float*)d_in[4];
    const float* Wc0    = (const float*)d_in[5];
    const float* bc0    = (const float*)d_in[6];
    const float* We_enc = (const float*)d_in[7];
    const float* We_hid = (const float*)d_in[8];
    const float* be     = (const float*)d_in[9];
    const float* Wi     = (const float*)d_in[10];
    const float* bi     = (const float*)d_in[11];
    const float* Wf     = (const float*)d_in[12];
    const float* bf     = (const float*)d_in[13];
    const float* Wo     = (const float*)d_in[14];
    const float* bo     = (const float*)d_in[15];
    const float* Wg     = (const float*)d_in[16];
    const float* bg     = (const float*)d_in[17];
    const float* Wcp    = (const float*)d_in[18];
    const float* bcp    = (const float*)d_in[19];
    const float* Whp    = (const float*)d_in[20];
    const float* bhp    = (const float*)d_in[21];
    const float* Wop    = (const float*)d_in[22];
    const float* bop    = (const float*)d_in[23];
    float* out = (float*)d_out;
    (void)We_hid; (void)be;   // softmax is invariant to the h-term: unused.

    // Workspace carve-up (floats). Total ~9.7M floats (~39 MB).
    float* w = (float*)d_ws;
    float* W4e_p = w; w += KH*N4P;       //   369,664
    float* W4h_p = w; w += KH*N4P;       //   369,664
    float* W4c_p = w; w += 2048*N4P;     // 2,490,368
    float* Whc_p = w; w += 2048*NH;      // 1,277,952
    float* b4p   = w; w += N4P;
    float* pb_b  = w; w += NPP;
    float* bhc   = w; w += NH;
    float* e_enc = w; w += Bb*Cc;
    float* ctxT  = w; w += Ff*64;        //   131,072
    float* hT    = w; w += Tt*Hh*64;     //   614,400  h_t, t=0..31, [t][col][b]
    float* E     = w; w += 31*Hh*64;     //   595,200  emb_prev, [t][j][b]
    float* c0T   = w; w += KH*64;        //    19,456  [col][b]
    float* gpre  = w; w += 31*N4P*64;    // 2,412,544  [t][n][b]
    float* partC = w; w += 8*N4P*64;     //   622,592  [ks][n][b]
    float* ppb   = w; w += 8*NPP*64;     //   172,032  [ks][n][b]
    float* tmpT  = w; w += 31*KOP*64;    //   603,136  [t][j][b]
    int*   flags = (int*)w; w += 128;    //   epoch flags (reset by k_pack)
    // init-phase aliases (dead before tmpT is written by k_gemm_tmp)
    float* meanT = tmpT;                 // 131,072
    float* parth = tmpT + 131072;        // 319,488 (fits 603,136)
    (void)ws_size; (void)in_sizes; (void)n_in; (void)out_size;

    k_pack<<<2048, 256, 0, stream>>>(Wi, Wf, Wo, Wg, bi, bf, bo, bg,
                                     bcp, bhp, bh0, bc0, Wh0, Wc0,
                                     W4e_p, W4h_p, W4c_p, Whc_p,
                                     b4p, pb_b, bhc, flags);
    k_meanT<<<dim3(8, 64), 256, 0, stream>>>(enc, meanT);
    k_eenc <<<dim3(25, 64), 256, 0, stream>>>(enc, We_enc, e_enc);
    k_embed<<<2400, 256, 0, stream>>>(caps, emb, E, out);
    k_ctx  <<<dim3(8, 64), 256, 0, stream>>>(enc, e_enc, ctxT);
    k_gemm_h0<<<dim3(13, 8), 192, 0, stream>>>(meanT, Whc_p, parth);
    k_h0fin2<<<64, 256, 0, stream>>>(parth, bhc, hT, c0T);
    k_gemm_C<<<dim3(19, 8), 256, 0, stream>>>(ctxT, W4c_p, partC);
    k_gemm_gpre<<<dim3(19, 31), 256, 0, stream>>>(E, W4e_p, partC, b4p, gpre);
    k_gemm_pb<<<dim3(7, 8), 192, 0, stream>>>(ctxT, Wcp, ppb);

    // Recurrence: cooperative launch for co-residency; custom flag sync inside.
    {
        void* rargs[] = { (void*)&W4h_p, (void*)&gpre, (void*)&c0T,
                          (void*)&hT, (void*)&flags };
        hipLaunchCooperativeKernel((const void*)k_recs, dim3(NWG), dim3(512),
                                   rargs, 0, stream);
    }

    k_gemm_tmp<<<dim3(7, 31), 192, 0, stream>>>(hT, Whp, E, ppb, pb_b, tmpT);
    k_predb<<<dim3(7, 31), 192, 0, stream>>>(tmpT, Wop, bop, out);
}

// Round 7
// 820.977 us; speedup vs baseline: 1.3518x; 1.3518x over previous
//
#include <hip/hip_runtime.h>
#include <math.h>

// Problem constants
#define Bb   64
#define Cc   100
#define Ff   2048
#define Tt   32
#define Hh   300
#define N4P  1216   // 4 gates * H padded to 19*64, n = 4*col + gate
#define KH   304    // H padded to 19*16
#define NPP  336
#define KOP  304    // 300 padded to 19*16
#define BOSi 1
#define NWG  75     // recurrence workgroups (75 * 4 hcols = 300)
#define NBIG 2240   // CH gemm width: 1216 (W4c) + 640 (Whc) + 384 (Wcp)
#define NH0  1216   // offset of h0/c0 cols in NBIG
#define NPB  1856   // offset of Wcp cols in NBIG

__device__ __forceinline__ float sigmf_(float x){ return 1.0f/(1.0f + expf(-x)); }

__device__ __forceinline__ void fma16_(const float4 av, const float4 bv, float acc[4][4]){
    acc[0][0] += av.x*bv.x; acc[0][1] += av.x*bv.y; acc[0][2] += av.x*bv.z; acc[0][3] += av.x*bv.w;
    acc[1][0] += av.y*bv.x; acc[1][1] += av.y*bv.y; acc[1][2] += av.y*bv.z; acc[1][3] += av.y*bv.w;
    acc[2][0] += av.z*bv.x; acc[2][1] += av.z*bv.y; acc[2][2] += av.z*bv.z; acc[2][3] += av.z*bv.w;
    acc[3][0] += av.w*bv.x; acc[3][1] += av.w*bv.y; acc[3][2] += av.w*bv.z; acc[3][3] += av.w*bv.w;
}

// ---------------------------------------------------------------------------
// FUSED-0: one launch, three independent jobs dispatched by blockIdx:
//   wg in [0,64):        per-b init: mean, e_enc, softmax, ctx  (reads enc)
//   wg in [64,64+2048):  weight pack (Wbig / W4e_p / W4h_p / biases / flags)
//   wg >= 64+2048:       embedding gather E + BOS row of out
// ---------------------------------------------------------------------------
#define NPACKWG 2048
#define TOTPACK (2048*NBIG + 2*KH*N4P + N4P + NPP + 2*Hh + 128)

__global__ __launch_bounds__(256) void k_fused0(
    const float* __restrict__ enc, const float* __restrict__ We_enc,
    const int* __restrict__ caps, const float* __restrict__ emb,
    const float* Wi, const float* Wf, const float* Wo, const float* Wg,
    const float* bi, const float* bf, const float* bo, const float* bg,
    const float* bcp, const float* bhp, const float* bh0, const float* bc0,
    const float* Wh0, const float* Wc0, const float* Wcp,
    float* Wbig, float* W4e_p, float* W4h_p,
    float* b4p, float* pb_b, float* bhc,
    float* meanT, float* ctxT, float* E, float* out, int* flags)
{
    const int wg = blockIdx.x, tid = threadIdx.x;

    if (wg < 64) {
        // ---- per-b init ----
        const int b = wg;
        __shared__ float swe[2048];
        __shared__ float sa[128];
        for (int i = tid; i < 2048; i += 256) swe[i] = We_enc[i];
        const float* pe = enc + (long)b*Cc*Ff;
        // mean over c (thread owns 8 f's)
        float macc[8] = {};
        for (int c = 0; c < Cc; c++) {
#pragma unroll
            for (int j = 0; j < 8; j++) macc[j] += pe[c*Ff + tid + j*256];
        }
#pragma unroll
        for (int j = 0; j < 8; j++) meanT[(tid + j*256)*64 + b] = macc[j]*(1.0f/Cc);
        __syncthreads();
        // e_enc: wave w owns c = w, w+4, ...
        const int w = tid >> 6, lane = tid & 63;
        for (int c = w; c < Cc; c += 4) {
            float ep = 0.0f;
            const float* pc = pe + (long)c*Ff;
#pragma unroll
            for (int j = 0; j < 32; j++) {
                const int f = lane + j*64;
                ep += pc[f]*swe[f];
            }
            for (int o = 32; o; o >>= 1) ep += __shfl_xor(ep, o);
            if (lane == 0) sa[c] = ep;
        }
        __syncthreads();
        // softmax (wave 0)
        if (tid < 64) {
            float v0 = sa[tid];
            float v1 = (tid + 64 < Cc) ? sa[tid+64] : -1e30f;
            float m = fmaxf(v0, v1);
            for (int o = 32; o; o >>= 1) m = fmaxf(m, __shfl_xor(m, o));
            float e0 = expf(v0 - m);
            float e1 = (tid + 64 < Cc) ? expf(v1 - m) : 0.0f;
            float ssum = e0 + e1;
            for (int o = 32; o; o >>= 1) ssum += __shfl_xor(ssum, o);
            float inv = 1.0f/ssum;
            sa[tid] = e0*inv;
            if (tid + 64 < Cc) sa[tid+64] = e1*inv;
        }
        __syncthreads();
        // ctx
#pragma unroll
        for (int j = 0; j < 8; j++) {
            const int f = tid + j*256;
            float acc = 0.0f;
#pragma unroll 10
            for (int c = 0; c < Cc; c++) acc += sa[c]*pe[c*Ff + f];
            ctxT[f*64 + b] = acc;
        }
        return;
    }

    if (wg < 64 + NPACKWG) {
        // ---- pack ----
        for (int idx = (wg-64)*256 + tid; idx < TOTPACK; idx += NPACKWG*256) {
            int i = idx;
            if (i < 2048*NBIG) {
                const int k = i / NBIG, n = i % NBIG;
                float v = 0.0f;
                if (n < N4P) {
                    const int c = n >> 2, g = n & 3;
                    const float* W = (g==0)?Wi:(g==1)?Wf:(g==2)?Wo:Wg;
                    if (c < Hh) v = W[(2*Hh + k)*Hh + c];
                } else if (n < NPB) {
                    const int m = n - NH0, col = m >> 1, g = m & 1;
                    if (col < Hh) v = (g ? Wc0 : Wh0)[k*Hh + col];
                } else {
                    const int j = n - NPB;
                    if (j < Hh) v = Wcp[k*Hh + j];
                }
                Wbig[i] = v;
                continue;
            }
            i -= 2048*NBIG;
            if (i < KH*N4P) {
                const int k = i / N4P, n = i % N4P, c = n >> 2, g = n & 3;
                const float* W = (g==0)?Wi:(g==1)?Wf:(g==2)?Wo:Wg;
                W4e_p[i] = (k < Hh && c < Hh) ? W[k*Hh + c] : 0.0f;
                continue;
            }
            i -= KH*N4P;
            if (i < KH*N4P) {
                const int k = i / N4P, n = i % N4P, c = n >> 2, g = n & 3;
                const float* W = (g==0)?Wi:(g==1)?Wf:(g==2)?Wo:Wg;
                W4h_p[i] = (k < Hh && c < Hh) ? W[(Hh + k)*Hh + c] : 0.0f;
                continue;
            }
            i -= KH*N4P;
            if (i < N4P) {
                const int c = i >> 2, g = i & 3;
                const float* bb = (g==0)?bi:(g==1)?bf:(g==2)?bo:bg;
                b4p[i] = (c < Hh) ? bb[c] : 0.0f;
                continue;
            }
            i -= N4P;
            if (i < NPP) {
                pb_b[i] = (i < Hh) ? (bcp[i] + bhp[i]) : 0.0f;
                continue;
            }
            i -= NPP;
            if (i < 2*Hh) {
                const int c = i >> 1, g = i & 1;
                bhc[i] = g ? bc0[c] : bh0[c];
                continue;
            }
            i -= 2*Hh;
            flags[i] = (i < NWG) ? 0 : 0x7fffffff;
        }
        return;
    }

    // ---- embed + bos ----
    {
        const int idx = (wg - 64 - NPACKWG)*256 + tid;
        const int nE = (Tt-1)*Hh*Bb;
        if (idx < nE) {
            const int j = idx % Hh;
            const int bt = idx / Hh;
            const int b = bt / (Tt-1), t = bt % (Tt-1);
            E[(t*Hh + j)*64 + b] = emb[(long)caps[b*Tt + t]*Hh + j];
        } else {
            const int r = idx - nE;
            if (r < Bb*Hh) {
                const int b = r / Hh, j = r % Hh;
                out[(b*Tt)*Hh + j] = emb[(long)BOSi*Hh + j];
            }
        }
        return;
    }
}

// ---------------------------------------------------------------------------
// CH GEMM: A(64 x 2048, k-major) @ Wbig (2048 x 2240). grid (35 nt, 8 ks).
// A per n-tile: nt in [19,29) -> meanT (h0/c0 cols), else ctxT (W4c, Wcp).
// Output partBig[ks][n][b].
// ---------------------------------------------------------------------------
__global__ __launch_bounds__(256) void k_gemm_CH(const float* __restrict__ meanT,
                                                 const float* __restrict__ ctxT,
                                                 const float* __restrict__ Wbig,
                                                 float* __restrict__ partBig)
{
    const int nt = blockIdx.x, ks = blockIdx.y, tid = threadIdx.x;
    const int n0 = nt*64, tx = tid & 15, ty = tid >> 4;
    const float* Asrc = (nt >= 19 && nt < 29) ? meanT : ctxT;
    __shared__ float As[16][64];
    __shared__ float Bs[16][64];
    float acc[4][4] = {};
    const int k0 = ks*256;
    for (int kb = 0; kb < 16; kb++) {
        const int kbase = k0 + kb*16;
#pragma unroll
        for (int i = 0; i < 4; i++) {
            int idx = tid + i*256;
            int kk = idx >> 6, bb = idx & 63;
            As[kk][bb] = Asrc[(kbase + kk)*64 + bb];
        }
#pragma unroll
        for (int i = 0; i < 4; i++) {
            int idx = tid + i*256;
            int kk = idx >> 6, nn = idx & 63;
            Bs[kk][nn] = Wbig[(long)(kbase + kk)*NBIG + n0 + nn];
        }
        __syncthreads();
#pragma unroll
        for (int kk = 0; kk < 16; kk++) {
            float4 av = *(const float4*)&As[kk][ty*4];
            float4 bv = *(const float4*)&Bs[kk][tx*4];
            fma16_(av, bv, acc);
        }
        __syncthreads();
    }
#pragma unroll
    for (int jn = 0; jn < 4; jn++) {
        float4 v = make_float4(acc[0][jn], acc[1][jn], acc[2][jn], acc[3][jn]);
        *(float4*)&partBig[((long)ks*NBIG + n0 + tx*4 + jn)*64 + ty*4] = v;
    }
}

// ---------------------------------------------------------------------------
// FUSED h0fin + gpre. 1D grid 589+64, 256 thr.
//   wg < 589: gpre[t][n][b] = (E_t @ W4e_p)[n][b] + sum_ks partBig[ks][n][b]
//             + b4p[n]   (nt = wg%19, t = wg/19)
//   else:     h0/c0 epilogue for b = wg-589.
// ---------------------------------------------------------------------------
__global__ __launch_bounds__(256) void k_h0gpre(const float* __restrict__ E,
                                                const float* __restrict__ W4e_p,
                                                const float* __restrict__ partBig,
                                                const float* __restrict__ b4p,
                                                const float* __restrict__ bhc,
                                                float* __restrict__ gpre,
                                                float* __restrict__ hT,
                                                float* __restrict__ c0T)
{
    const int wg = blockIdx.x, tid = threadIdx.x;
    if (wg >= 589) {
        const int b = wg - 589;
        for (int col = tid; col < Hh; col += 256) {
            float sh = bhc[2*col], sc = bhc[2*col+1];
            for (int ks = 0; ks < 8; ks++) {
                sh += partBig[((long)ks*NBIG + NH0 + 2*col + 0)*64 + b];
                sc += partBig[((long)ks*NBIG + NH0 + 2*col + 1)*64 + b];
            }
            hT[(0*Hh + col)*64 + b] = tanhf(sh);
            c0T[col*64 + b] = tanhf(sc);
        }
        return;
    }
    const int nt = wg % 19, t = wg / 19;
    const int n0 = nt*64, tx = tid & 15, ty = tid >> 4;
    __shared__ float As[16][64];
    __shared__ float Bs[16][64];
    float acc[4][4] = {};
    for (int kb = 0; kb < 19; kb++) {
        const int kbase = kb*16;
#pragma unroll
        for (int i = 0; i < 4; i++) {
            int idx = tid + i*256;
            int kk = idx >> 6, bb = idx & 63, j = kbase + kk;
            As[kk][bb] = (j < Hh) ? E[(t*Hh + j)*64 + bb] : 0.0f;
        }
#pragma unroll
        for (int i = 0; i < 4; i++) {
            int idx = tid + i*256;
            int kk = idx >> 6, nn = idx & 63;
            Bs[kk][nn] = W4e_p[(kbase + kk)*N4P + n0 + nn];
        }
        __syncthreads();
#pragma unroll
        for (int kk = 0; kk < 16; kk++) {
            float4 av = *(const float4*)&As[kk][ty*4];
            float4 bv = *(const float4*)&Bs[kk][tx*4];
            fma16_(av, bv, acc);
        }
        __syncthreads();
    }
#pragma unroll
    for (int jn = 0; jn < 4; jn++) {
        const int n = n0 + tx*4 + jn;
        float4 ps = make_float4(0,0,0,0);
        for (int ks = 0; ks < 8; ks++) {
            const float4 v = *(const float4*)&partBig[((long)ks*NBIG + n)*64 + ty*4];
            ps.x += v.x; ps.y += v.y; ps.z += v.z; ps.w += v.w;
        }
        const float bv = b4p[n];
        float4 o;
        o.x = acc[0][jn] + ps.x + bv;
        o.y = acc[1][jn] + ps.y + bv;
        o.z = acc[2][jn] + ps.z + bv;
        o.w = acc[3][jn] + ps.w + bv;
        *(float4*)&gpre[((long)t*N4P + n)*64 + ty*4] = o;
    }
}

// ---------------------------------------------------------------------------
// Recurrence, flag-synced. 75 WGs x 512 thr (cooperative: co-residency).
// WG s owns h-cols [4s,4s+4) = 16 gate cols. Wave w (0..7) owns a DISTINCT
// k-range (38/34 k) and computes partials for ALL 16 gate cols from direct
// agent loads of h (38 independent, fully pipelined; weights LDS-broadcast).
// psum[8][16][64] reduce; threads<256 (hc=tid>>6) do gates + cell + h store.
// ---------------------------------------------------------------------------
__global__ __launch_bounds__(512) void k_recs(const float* __restrict__ W4h_p,
                                              const float* __restrict__ gpre,
                                              const float* __restrict__ c0T,
                                              float* __restrict__ hT,
                                              int* __restrict__ flags)
{
    const int s = blockIdx.x, tid = threadIdx.x;
    const int b = tid & 63, w = tid >> 6;
    __shared__ float wlds[300][16];
    __shared__ float psum[8][16][64];

    for (int i = tid; i < 300*16; i += 512)
        wlds[i >> 4][i & 15] = W4h_p[(i >> 4)*N4P + 16*s + (i & 15)];

    float cst = 0.0f;
    if (tid < 256) cst = c0T[(4*s + (tid >> 6))*64 + b];
    __syncthreads();

    const int k0 = w*38;
    const int klen = (w == 7) ? 34 : 38;

    for (int t = 1; t < Tt; t++) {
        // prefetch gate bias for owned outputs
        float gpv0 = 0.f, gpv1 = 0.f, gpv2 = 0.f, gpv3 = 0.f;
        if (tid < 256) {
            const float* gp = gpre + ((long)(t-1)*N4P + 16*s + 4*(tid >> 6))*64 + b;
            gpv0 = gp[0]; gpv1 = gp[64]; gpv2 = gp[128]; gpv3 = gp[192];
        }
        // wait for h[t-1] from all WGs
        if (t >= 2) {
            if (tid < 64) {
                for (;;) {
                    const int v0 = __hip_atomic_load(&flags[tid], __ATOMIC_RELAXED,
                                                     __HIP_MEMORY_SCOPE_AGENT);
                    const int v1 = __hip_atomic_load(&flags[tid+64], __ATOMIC_RELAXED,
                                                     __HIP_MEMORY_SCOPE_AGENT);
                    if (__all(v0 >= t-1 && v1 >= t-1)) break;
                    __builtin_amdgcn_s_sleep(1);
                }
            }
            __syncthreads();
        }
        // GEMV partial: this wave's k-range, all 16 gate cols
        float a[16] = {0,0,0,0,0,0,0,0,0,0,0,0,0,0,0,0};
        {
            const float* hp = hT + (long)(t-1)*(Hh*64) + k0*64 + b;
#pragma unroll 2
            for (int k = 0; k < klen; k++) {
                const float hv = __hip_atomic_load(hp + k*64, __ATOMIC_RELAXED,
                                                   __HIP_MEMORY_SCOPE_AGENT);
                const float4 w0 = *(const float4*)&wlds[k0+k][0];
                const float4 w1 = *(const float4*)&wlds[k0+k][4];
                const float4 w2 = *(const float4*)&wlds[k0+k][8];
                const float4 w3 = *(const float4*)&wlds[k0+k][12];
                a[0]  += hv*w0.x; a[1]  += hv*w0.y; a[2]  += hv*w0.z; a[3]  += hv*w0.w;
                a[4]  += hv*w1.x; a[5]  += hv*w1.y; a[6]  += hv*w1.z; a[7]  += hv*w1.w;
                a[8]  += hv*w2.x; a[9]  += hv*w2.y; a[10] += hv*w2.z; a[11] += hv*w2.w;
                a[12] += hv*w3.x; a[13] += hv*w3.y; a[14] += hv*w3.z; a[15] += hv*w3.w;
            }
        }
#pragma unroll
        for (int j = 0; j < 16; j++) psum[w][j][b] = a[j];
        __syncthreads();
        if (tid < 256) {
            const int hc = tid >> 6;
            float g0 = gpv0, g1 = gpv1, g2 = gpv2, g3 = gpv3;
#pragma unroll
            for (int ww = 0; ww < 8; ww++) {
                g0 += psum[ww][4*hc+0][b];
                g1 += psum[ww][4*hc+1][b];
                g2 += psum[ww][4*hc+2][b];
                g3 += psum[ww][4*hc+3][b];
            }
            const float ig = sigmf_(g0), fg = sigmf_(g1), og = sigmf_(g2);
            const float gg = tanhf(g3);
            cst = fg*cst + ig*gg;
            const float h = og*tanhf(cst);
            __hip_atomic_store(&hT[(long)t*(Hh*64) + (4*s + hc)*64 + b], h,
                               __ATOMIC_RELAXED, __HIP_MEMORY_SCOPE_AGENT);
        }
        __syncthreads();   // drains h stores (vmcnt 0 before barrier)
        if (tid == 0 && t < Tt-1)
            __hip_atomic_store(&flags[s], t, __ATOMIC_RELAXED,
                               __HIP_MEMORY_SCOPE_AGENT);
    }
}

// ---------------------------------------------------------------------------
// tmp[t][j][b] = E[t][j][b] + (h_{t+1} @ Whp)[j][b] + pbias[j][b].
// grid (7 nt, 31 t), 192 thr.
// ---------------------------------------------------------------------------
__global__ __launch_bounds__(192) void k_gemm_tmp(const float* hT, const float* Whp,
                                                  const float* E, const float* partBig,
                                                  const float* pb_b, float* tmpT)
{
    const int nt = blockIdx.x, ti = blockIdx.y, tid = threadIdx.x;
    const int n0 = nt*48, tx = tid % 12, ty = tid / 12;
    __shared__ float As[16][64];
    __shared__ float Bs[16][48];
    float acc[4][4] = {};
    for (int kb = 0; kb < 19; kb++) {
        const int kbase = kb*16;
        for (int idx = tid; idx < 1024; idx += 192) {
            int kk = idx >> 6, bb = idx & 63, j = kbase + kk;
            As[kk][bb] = (j < Hh) ? hT[((ti+1)*Hh + j)*64 + bb] : 0.0f;
        }
        for (int idx = tid; idx < 768; idx += 192) {
            int kk = idx / 48, nn = idx % 48, j = kbase + kk, n = n0 + nn;
            Bs[kk][nn] = (j < Hh && n < Hh) ? Whp[j*Hh + n] : 0.0f;
        }
        __syncthreads();
#pragma unroll
        for (int kk = 0; kk < 16; kk++) {
            float4 av = *(const float4*)&As[kk][ty*4];
            float4 bv = *(const float4*)&Bs[kk][tx*4];
            fma16_(av, bv, acc);
        }
        __syncthreads();
    }
#pragma unroll
    for (int i = 0; i < 4; i++) {
        const int bb = ty*4 + i;
#pragma unroll
        for (int j = 0; j < 4; j++) {
            const int n = n0 + tx*4 + j;
            if (n < KOP) {
                float v = acc[i][j];
                if (n < Hh) {
                    float pb = pb_b[n];
                    for (int ks = 0; ks < 8; ks++)
                        pb += partBig[((long)ks*NBIG + NPB + n)*64 + bb];
                    v += E[(ti*Hh + n)*64 + bb] + pb;
                }
                tmpT[(ti*KOP + n)*64 + bb] = v;
            }
        }
    }
}

// Stage B: out[:, t+1, :] = tmp @ Wop + bop. grid (7, 31).
__global__ __launch_bounds__(192) void k_predb(const float* tmpT, const float* Wop,
                                               const float* bop, float* out)
{
    const int nt = blockIdx.x, ti = blockIdx.y, tid = threadIdx.x;
    const int n0 = nt*48, tx = tid % 12, ty = tid / 12;
    __shared__ float As[16][64];
    __shared__ float Bs[16][48];
    float acc[4][4] = {};
    const float* Asrc = tmpT + ti*KOP*64;

    for (int kb = 0; kb < 19; kb++) {
        const int kbase = kb*16;
        for (int idx = tid; idx < 1024; idx += 192) {
            int kk = idx >> 6, bb = idx & 63;
            As[kk][bb] = Asrc[(kbase + kk)*64 + bb];
        }
        for (int idx = tid; idx < 768; idx += 192) {
            int kk = idx / 48, nn = idx % 48, j = kbase + kk, n = n0 + nn;
            Bs[kk][nn] = (j < Hh && n < Hh) ? Wop[j*Hh + n] : 0.0f;
        }
        __syncthreads();
#pragma unroll
        for (int kk = 0; kk < 16; kk++) {
            float4 av = *(const float4*)&As[kk][ty*4];
            float4 bv = *(const float4*)&Bs[kk][tx*4];
            fma16_(av, bv, acc);
        }
        __syncthreads();
    }
#pragma unroll
    for (int i = 0; i < 4; i++) {
        const int bb = ty*4 + i;
#pragma unroll
        for (int j = 0; j < 4; j++) {
            const int n = n0 + tx*4 + j;
            if (n < Hh)
                out[(bb*Tt + (ti+1))*Hh + n] = acc[i][j] + bop[n];
        }
    }
}

// ---------------------------------------------------------------------------
extern "C" void kernel_launch(void* const* d_in, const int* in_sizes, int n_in,
                              void* d_out, int out_size, void* d_ws, size_t ws_size,
                              hipStream_t stream)
{
    const float* enc    = (const float*)d_in[0];
    const int*   caps   = (const int*)  d_in[1];
    const float* emb    = (const float*)d_in[2];
    const float* Wh0    = (const float*)d_in[3];
    const float* bh0    = (const float*)d_in[4];
    const float* Wc0    = (const float*)d_in[5];
    const float* bc0    = (const float*)d_in[6];
    const float* We_enc = (const float*)d_in[7];
    const float* We_hid = (const float*)d_in[8];
    const float* be     = (const float*)d_in[9];
    const float* Wi     = (const float*)d_in[10];
    const float* bi     = (const float*)d_in[11];
    const float* Wf     = (const float*)d_in[12];
    const float* bf     = (const float*)d_in[13];
    const float* Wo     = (const float*)d_in[14];
    const float* bo     = (const float*)d_in[15];
    const float* Wg     = (const float*)d_in[16];
    const float* bg     = (const float*)d_in[17];
    const float* Wcp    = (const float*)d_in[18];
    const float* bcp    = (const float*)d_in[19];
    const float* Whp    = (const float*)d_in[20];
    const float* bhp    = (const float*)d_in[21];
    const float* Wop    = (const float*)d_in[22];
    const float* bop    = (const float*)d_in[23];
    float* out = (float*)d_out;
    (void)We_hid; (void)be;   // softmax is invariant to the h-term: unused.

    // Workspace carve-up (floats). ~8.45M floats (~34 MB).
    float* w = (float*)d_ws;
    float* Wbig  = w; w += 2048*NBIG;    // 4,587,520 (aliased by gpre later)
    float* W4e_p = w; w += KH*N4P;       //   369,664
    float* W4h_p = w; w += KH*N4P;       //   369,664
    float* b4p   = w; w += N4P;
    float* pb_b  = w; w += NPP;
    float* bhc   = w; w += 2*Hh;
    float* ctxT  = w; w += Ff*64;        //   131,072
    float* hT    = w; w += Tt*Hh*64;     //   614,400  [t][col][b]
    float* E     = w; w += 31*Hh*64;     //   595,200  [t][j][b]
    float* c0T   = w; w += KH*64;        //    19,456
    float* partBig = w; w += 8*NBIG*64;  // 1,146,880  [ks][n][b]
    float* tmpT  = w; w += 31*KOP*64;    //   603,136  [t][j][b]
    int*   flags = (int*)w; w += 128;
    // time-disjoint aliases:
    float* gpre  = Wbig;    // 31*N4P*64 = 2,412,544 <= 4,587,520 (Wbig dead after CH)
    float* meanT = tmpT;    // 131,072 (tmpT written after CH reads meanT)
    (void)ws_size; (void)in_sizes; (void)n_in; (void)out_size;

    // 1. fused init + pack + embed
    k_fused0<<<64 + NPACKWG + 2400, 256, 0, stream>>>(
        enc, We_enc, caps, emb,
        Wi, Wf, Wo, Wg, bi, bf, bo, bg, bcp, bhp, bh0, bc0, Wh0, Wc0, Wcp,
        Wbig, W4e_p, W4h_p, b4p, pb_b, bhc,
        meanT, ctxT, E, out, flags);

    // 2. combined C/h0/pb GEMM
    k_gemm_CH<<<dim3(35, 8), 256, 0, stream>>>(meanT, ctxT, Wbig, partBig);

    // 3. h0 epilogue + gpre (gpre aliases Wbig -- Wbig is dead now)
    k_h0gpre<<<653, 256, 0, stream>>>(E, W4e_p, partBig, b4p, bhc, gpre, hT, c0T);

    // 4. recurrence (cooperative for co-residency; custom flag sync inside)
    {
        void* rargs[] = { (void*)&W4h_p, (void*)&gpre, (void*)&c0T,
                          (void*)&hT, (void*)&flags };
        hipLaunchCooperativeKernel((const void*)k_recs, dim3(NWG), dim3(512),
                                   rargs, 0, stream);
    }

    // 5-6. deferred prediction
    k_gemm_tmp<<<dim3(7, 31), 192, 0, stream>>>(hT, Whp, E, partBig, pb_b, tmpT);
    k_predb<<<dim3(7, 31), 192, 0, stream>>>(tmpT, Wop, bop, out);
}

// Round 9
// 741.191 us; speedup vs baseline: 1.4973x; 1.1076x over previous
//
#include <hip/hip_runtime.h>
#include <math.h>

// Problem constants
#define Bb   64
#define Cc   100
#define Ff   2048
#define Tt   32
#define Hh   300
#define N4P  1216   // 4 gates * H padded to 19*64, n = 4*col + gate
#define KH   304    // H padded to 19*16 (also per-t row stride of hT)
#define NPP  336
#define KOP  304    // 300 padded to 19*16
#define BOSi 1
#define NWG  75     // recurrence workgroups (75 * 4 hcols = 300)
#define NBIG 2240   // CH gemm width: 1216 (W4c) + 640 (Whc) + 384 (Wcp)
#define NH0  1216   // offset of h0/c0 cols in NBIG
#define NPB  1856   // offset of Wcp cols in NBIG

__device__ __forceinline__ float sigmf_(float x){ return 1.0f/(1.0f + expf(-x)); }

__device__ __forceinline__ void fma16_(const float4 av, const float4 bv, float acc[4][4]){
    acc[0][0] += av.x*bv.x; acc[0][1] += av.x*bv.y; acc[0][2] += av.x*bv.z; acc[0][3] += av.x*bv.w;
    acc[1][0] += av.y*bv.x; acc[1][1] += av.y*bv.y; acc[1][2] += av.y*bv.z; acc[1][3] += av.y*bv.w;
    acc[2][0] += av.z*bv.x; acc[2][1] += av.z*bv.y; acc[2][2] += av.z*bv.z; acc[2][3] += av.z*bv.w;
    acc[3][0] += av.w*bv.x; acc[3][1] += av.w*bv.y; acc[3][2] += av.w*bv.z; acc[3][3] += av.w*bv.w;
}

// ---------------------------------------------------------------------------
// FUSED-0: one launch, three independent jobs dispatched by blockIdx:
//   wg in [0,64):        per-b init: mean, e_enc, softmax, ctx  (reads enc)
//   wg in [64,64+2048):  weight pack + hT pad-row zeroing + flag init
//   wg >= 64+2048:       embedding gather E + BOS row of out
// ---------------------------------------------------------------------------
#define NPACKWG 2048
#define TOTPACK (2048*NBIG + 2*KH*N4P + N4P + NPP + 2*Hh + Tt*256 + 128)

__global__ __launch_bounds__(256) void k_fused0(
    const float* __restrict__ enc, const float* __restrict__ We_enc,
    const int* __restrict__ caps, const float* __restrict__ emb,
    const float* Wi, const float* Wf, const float* Wo, const float* Wg,
    const float* bi, const float* bf, const float* bo, const float* bg,
    const float* bcp, const float* bhp, const float* bh0, const float* bc0,
    const float* Wh0, const float* Wc0, const float* Wcp,
    float* Wbig, float* W4e_p, float* W4h_p,
    float* b4p, float* pb_b, float* bhc,
    float* meanT, float* ctxT, float* E, float* out, float* hT, int* flags)
{
    const int wg = blockIdx.x, tid = threadIdx.x;

    if (wg < 64) {
        // ---- per-b init ----
        const int b = wg;
        __shared__ float swe[2048];
        __shared__ float sa[128];
        for (int i = tid; i < 2048; i += 256) swe[i] = We_enc[i];
        const float* pe = enc + (long)b*Cc*Ff;
        float macc[8] = {};
        for (int c = 0; c < Cc; c++) {
#pragma unroll
            for (int j = 0; j < 8; j++) macc[j] += pe[c*Ff + tid + j*256];
        }
#pragma unroll
        for (int j = 0; j < 8; j++) meanT[(tid + j*256)*64 + b] = macc[j]*(1.0f/Cc);
        __syncthreads();
        const int w = tid >> 6, lane = tid & 63;
        for (int c = w; c < Cc; c += 4) {
            float ep = 0.0f;
            const float* pc = pe + (long)c*Ff;
#pragma unroll
            for (int j = 0; j < 32; j++) {
                const int f = lane + j*64;
                ep += pc[f]*swe[f];
            }
            for (int o = 32; o; o >>= 1) ep += __shfl_xor(ep, o);
            if (lane == 0) sa[c] = ep;
        }
        __syncthreads();
        if (tid < 64) {
            float v0 = sa[tid];
            float v1 = (tid + 64 < Cc) ? sa[tid+64] : -1e30f;
            float m = fmaxf(v0, v1);
            for (int o = 32; o; o >>= 1) m = fmaxf(m, __shfl_xor(m, o));
            float e0 = expf(v0 - m);
            float e1 = (tid + 64 < Cc) ? expf(v1 - m) : 0.0f;
            float ssum = e0 + e1;
            for (int o = 32; o; o >>= 1) ssum += __shfl_xor(ssum, o);
            float inv = 1.0f/ssum;
            sa[tid] = e0*inv;
            if (tid + 64 < Cc) sa[tid+64] = e1*inv;
        }
        __syncthreads();
#pragma unroll
        for (int j = 0; j < 8; j++) {
            const int f = tid + j*256;
            float acc = 0.0f;
#pragma unroll 10
            for (int c = 0; c < Cc; c++) acc += sa[c]*pe[c*Ff + f];
            ctxT[f*64 + b] = acc;
        }
        return;
    }

    if (wg < 64 + NPACKWG) {
        // ---- pack ----
        for (int idx = (wg-64)*256 + tid; idx < TOTPACK; idx += NPACKWG*256) {
            int i = idx;
            if (i < 2048*NBIG) {
                const int k = i / NBIG, n = i % NBIG;
                float v = 0.0f;
                if (n < N4P) {
                    const int c = n >> 2, g = n & 3;
                    const float* W = (g==0)?Wi:(g==1)?Wf:(g==2)?Wo:Wg;
                    if (c < Hh) v = W[(2*Hh + k)*Hh + c];
                } else if (n < NPB) {
                    const int m = n - NH0, col = m >> 1, g = m & 1;
                    if (col < Hh) v = (g ? Wc0 : Wh0)[k*Hh + col];
                } else {
                    const int j = n - NPB;
                    if (j < Hh) v = Wcp[k*Hh + j];
                }
                Wbig[i] = v;
                continue;
            }
            i -= 2048*NBIG;
            if (i < KH*N4P) {
                const int k = i / N4P, n = i % N4P, c = n >> 2, g = n & 3;
                const float* W = (g==0)?Wi:(g==1)?Wf:(g==2)?Wo:Wg;
                W4e_p[i] = (k < Hh && c < Hh) ? W[k*Hh + c] : 0.0f;
                continue;
            }
            i -= KH*N4P;
            if (i < KH*N4P) {
                const int k = i / N4P, n = i % N4P, c = n >> 2, g = n & 3;
                const float* W = (g==0)?Wi:(g==1)?Wf:(g==2)?Wo:Wg;
                W4h_p[i] = (k < Hh && c < Hh) ? W[(Hh + k)*Hh + c] : 0.0f;
                continue;
            }
            i -= KH*N4P;
            if (i < N4P) {
                const int c = i >> 2, g = i & 3;
                const float* bb = (g==0)?bi:(g==1)?bf:(g==2)?bo:bg;
                b4p[i] = (c < Hh) ? bb[c] : 0.0f;
                continue;
            }
            i -= N4P;
            if (i < NPP) {
                pb_b[i] = (i < Hh) ? (bcp[i] + bhp[i]) : 0.0f;
                continue;
            }
            i -= NPP;
            if (i < 2*Hh) {
                const int c = i >> 1, g = i & 1;
                bhc[i] = g ? bc0[c] : bh0[c];
                continue;
            }
            i -= 2*Hh;
            if (i < Tt*256) {
                // zero hT pad rows 300..303 of every step (0x0 weight rows)
                const int t = i >> 8, r = i & 255;
                hT[(long)t*(KH*64) + 300*64 + r] = 0.0f;
                continue;
            }
            i -= Tt*256;
            flags[i] = (i < NWG) ? 0 : 0x7fffffff;   // reset every launch
        }
        return;
    }

    // ---- embed + bos ----
    {
        const int idx = (wg - 64 - NPACKWG)*256 + tid;
        const int nE = (Tt-1)*Hh*Bb;
        if (idx < nE) {
            const int j = idx % Hh;
            const int bt = idx / Hh;
            const int b = bt / (Tt-1), t = bt % (Tt-1);
            E[(t*Hh + j)*64 + b] = emb[(long)caps[b*Tt + t]*Hh + j];
        } else {
            const int r = idx - nE;
            if (r < Bb*Hh) {
                const int b = r / Hh, j = r % Hh;
                out[(b*Tt)*Hh + j] = emb[(long)BOSi*Hh + j];
            }
        }
        return;
    }
}

// ---------------------------------------------------------------------------
// CH GEMM: A(64 x 2048, k-major) @ Wbig (2048 x 2240). grid (35 nt, 8 ks).
// A per n-tile: nt in [19,29) -> meanT (h0/c0 cols), else ctxT (W4c, Wcp).
// Output partBig[ks][n][b].
// ---------------------------------------------------------------------------
__global__ __launch_bounds__(256) void k_gemm_CH(const float* __restrict__ meanT,
                                                 const float* __restrict__ ctxT,
                                                 const float* __restrict__ Wbig,
                                                 float* __restrict__ partBig)
{
    const int nt = blockIdx.x, ks = blockIdx.y, tid = threadIdx.x;
    const int n0 = nt*64, tx = tid & 15, ty = tid >> 4;
    const float* Asrc = (nt >= 19 && nt < 29) ? meanT : ctxT;
    __shared__ float As[16][64];
    __shared__ float Bs[16][64];
    float acc[4][4] = {};
    const int k0 = ks*256;
    for (int kb = 0; kb < 16; kb++) {
        const int kbase = k0 + kb*16;
#pragma unroll
        for (int i = 0; i < 4; i++) {
            int idx = tid + i*256;
            int kk = idx >> 6, bb = idx & 63;
            As[kk][bb] = Asrc[(kbase + kk)*64 + bb];
        }
#pragma unroll
        for (int i = 0; i < 4; i++) {
            int idx = tid + i*256;
            int kk = idx >> 6, nn = idx & 63;
            Bs[kk][nn] = Wbig[(long)(kbase + kk)*NBIG + n0 + nn];
        }
        __syncthreads();
#pragma unroll
        for (int kk = 0; kk < 16; kk++) {
            float4 av = *(const float4*)&As[kk][ty*4];
            float4 bv = *(const float4*)&Bs[kk][tx*4];
            fma16_(av, bv, acc);
        }
        __syncthreads();
    }
#pragma unroll
    for (int jn = 0; jn < 4; jn++) {
        float4 v = make_float4(acc[0][jn], acc[1][jn], acc[2][jn], acc[3][jn]);
        *(float4*)&partBig[((long)ks*NBIG + n0 + tx*4 + jn)*64 + ty*4] = v;
    }
}

// ---------------------------------------------------------------------------
// FUSED h0fin + gpre. 1D grid 589+64, 256 thr.
// ---------------------------------------------------------------------------
__global__ __launch_bounds__(256) void k_h0gpre(const float* __restrict__ E,
                                                const float* __restrict__ W4e_p,
                                                const float* __restrict__ partBig,
                                                const float* __restrict__ b4p,
                                                const float* __restrict__ bhc,
                                                float* __restrict__ gpre,
                                                float* __restrict__ hT,
                                                float* __restrict__ c0T)
{
    const int wg = blockIdx.x, tid = threadIdx.x;
    if (wg >= 589) {
        const int b = wg - 589;
        for (int col = tid; col < Hh; col += 256) {
            float sh = bhc[2*col], sc = bhc[2*col+1];
            for (int ks = 0; ks < 8; ks++) {
                sh += partBig[((long)ks*NBIG + NH0 + 2*col + 0)*64 + b];
                sc += partBig[((long)ks*NBIG + NH0 + 2*col + 1)*64 + b];
            }
            hT[col*64 + b] = tanhf(sh);          // t = 0 (stride KH per t)
            c0T[col*64 + b] = tanhf(sc);
        }
        return;
    }
    const int nt = wg % 19, t = wg / 19;
    const int n0 = nt*64, tx = tid & 15, ty = tid >> 4;
    __shared__ float As[16][64];
    __shared__ float Bs[16][64];
    float acc[4][4] = {};
    for (int kb = 0; kb < 19; kb++) {
        const int kbase = kb*16;
#pragma unroll
        for (int i = 0; i < 4; i++) {
            int idx = tid + i*256;
            int kk = idx >> 6, bb = idx & 63, j = kbase + kk;
            As[kk][bb] = (j < Hh) ? E[(t*Hh + j)*64 + bb] : 0.0f;
        }
#pragma unroll
        for (int i = 0; i < 4; i++) {
            int idx = tid + i*256;
            int kk = idx >> 6, nn = idx & 63;
            Bs[kk][nn] = W4e_p[(kbase + kk)*N4P + n0 + nn];
        }
        __syncthreads();
#pragma unroll
        for (int kk = 0; kk < 16; kk++) {
            float4 av = *(const float4*)&As[kk][ty*4];
            float4 bv = *(const float4*)&Bs[kk][tx*4];
            fma16_(av, bv, acc);
        }
        __syncthreads();
    }
#pragma unroll
    for (int jn = 0; jn < 4; jn++) {
        const int n = n0 + tx*4 + jn;
        float4 ps = make_float4(0,0,0,0);
        for (int ks = 0; ks < 8; ks++) {
            const float4 v = *(const float4*)&partBig[((long)ks*NBIG + n)*64 + ty*4];
            ps.x += v.x; ps.y += v.y; ps.z += v.z; ps.w += v.w;
        }
        const float bv = b4p[n];
        float4 o;
        o.x = acc[0][jn] + ps.x + bv;
        o.y = acc[1][jn] + ps.y + bv;
        o.z = acc[2][jn] + ps.z + bv;
        o.w = acc[3][jn] + ps.w + bv;
        *(float4*)&gpre[((long)t*N4P + n)*64 + ty*4] = o;
    }
}

// ---------------------------------------------------------------------------
// Recurrence, flag-synced, cooperative launch (co-residency guaranteed; no
// grid.sync used). Wave w owns k-range [38w, 38w+38) (KH=304 = 8*38; rows
// 300..303 are zero weights x zeroed h pads). All 38 h loads batched into
// registers BEFORE the FMA loop -> single L3 latency exposure per step.
// ---------------------------------------------------------------------------
__global__ __launch_bounds__(512) void k_recs(const float* __restrict__ W4h_p,
                                              const float* __restrict__ gpre,
                                              const float* __restrict__ c0T,
                                              float* __restrict__ hT,
                                              int* __restrict__ flags)
{
    const int s = blockIdx.x, tid = threadIdx.x;
    const int b = tid & 63, w = tid >> 6;
    __shared__ float wlds[KH][16];
    __shared__ float psum[8][16][64];

    for (int i = tid; i < KH*16; i += 512)
        wlds[i >> 4][i & 15] = W4h_p[(i >> 4)*N4P + 16*s + (i & 15)];

    float cst = 0.0f;
    if (tid < 256) cst = c0T[(4*s + (tid >> 6))*64 + b];
    __syncthreads();

    const int k0 = w*38;

    for (int t = 1; t < Tt; t++) {
        // prefetch gate bias for owned outputs
        float gpv0 = 0.f, gpv1 = 0.f, gpv2 = 0.f, gpv3 = 0.f;
        if (tid < 256) {
            const float* gp = gpre + ((long)(t-1)*N4P + 16*s + 4*(tid >> 6))*64 + b;
            gpv0 = gp[0]; gpv1 = gp[64]; gpv2 = gp[128]; gpv3 = gp[192];
        }
        // wait for h[t-1] from all WGs
        if (t >= 2) {
            if (tid < 64) {
                for (;;) {
                    const int v0 = __hip_atomic_load(&flags[tid], __ATOMIC_RELAXED,
                                                     __HIP_MEMORY_SCOPE_AGENT);
                    const int v1 = __hip_atomic_load(&flags[tid+64], __ATOMIC_RELAXED,
                                                     __HIP_MEMORY_SCOPE_AGENT);
                    if (__all(v0 >= t-1 && v1 >= t-1)) break;
                    __builtin_amdgcn_s_sleep(1);
                }
            }
            __syncthreads();
        }
        // batch-load this wave's h k-range: 38 independent loads in flight
        float hreg[38];
        {
            const float* hp = hT + (long)(t-1)*(KH*64) + k0*64 + b;
#pragma unroll
            for (int k = 0; k < 38; k++)
                hreg[k] = __hip_atomic_load(hp + k*64, __ATOMIC_RELAXED,
                                            __HIP_MEMORY_SCOPE_AGENT);
        }
        // GEMV partial: all 16 gate cols
        float a[16] = {0,0,0,0,0,0,0,0,0,0,0,0,0,0,0,0};
#pragma unroll
        for (int k = 0; k < 38; k++) {
            const float hv = hreg[k];
            const float4 w0 = *(const float4*)&wlds[k0+k][0];
            const float4 w1 = *(const float4*)&wlds[k0+k][4];
            const float4 w2 = *(const float4*)&wlds[k0+k][8];
            const float4 w3 = *(const float4*)&wlds[k0+k][12];
            a[0]  += hv*w0.x; a[1]  += hv*w0.y; a[2]  += hv*w0.z; a[3]  += hv*w0.w;
            a[4]  += hv*w1.x; a[5]  += hv*w1.y; a[6]  += hv*w1.z; a[7]  += hv*w1.w;
            a[8]  += hv*w2.x; a[9]  += hv*w2.y; a[10] += hv*w2.z; a[11] += hv*w2.w;
            a[12] += hv*w3.x; a[13] += hv*w3.y; a[14] += hv*w3.z; a[15] += hv*w3.w;
        }
#pragma unroll
        for (int j = 0; j < 16; j++) psum[w][j][b] = a[j];
        __syncthreads();
        if (tid < 256) {
            const int hc = tid >> 6;
            float g0 = gpv0, g1 = gpv1, g2 = gpv2, g3 = gpv3;
#pragma unroll
            for (int ww = 0; ww < 8; ww++) {
                g0 += psum[ww][4*hc+0][b];
                g1 += psum[ww][4*hc+1][b];
                g2 += psum[ww][4*hc+2][b];
                g3 += psum[ww][4*hc+3][b];
            }
            const float ig = sigmf_(g0), fg = sigmf_(g1), og = sigmf_(g2);
            const float gg = tanhf(g3);
            cst = fg*cst + ig*gg;
            const float h = og*tanhf(cst);
            __hip_atomic_store(&hT[(long)t*(KH*64) + (4*s + hc)*64 + b], h,
                               __ATOMIC_RELAXED, __HIP_MEMORY_SCOPE_AGENT);
        }
        __syncthreads();   // drains h stores (vmcnt 0 before barrier)
        if (tid == 0 && t < Tt-1)
            __hip_atomic_store(&flags[s], t, __ATOMIC_RELAXED,
                               __HIP_MEMORY_SCOPE_AGENT);
    }
}

// ---------------------------------------------------------------------------
// tmp[t][j][b] = E[t][j][b] + (h_{t+1} @ Whp)[j][b] + pbias[j][b].
// grid (7 nt, 31 t), 192 thr.
// ---------------------------------------------------------------------------
__global__ __launch_bounds__(192) void k_gemm_tmp(const float* hT, const float* Whp,
                                                  const float* E, const float* partBig,
                                                  const float* pb_b, float* tmpT)
{
    const int nt = blockIdx.x, ti = blockIdx.y, tid = threadIdx.x;
    const int n0 = nt*48, tx = tid % 12, ty = tid / 12;
    __shared__ float As[16][64];
    __shared__ float Bs[16][48];
    float acc[4][4] = {};
    for (int kb = 0; kb < 19; kb++) {
        const int kbase = kb*16;
        for (int idx = tid; idx < 1024; idx += 192) {
            int kk = idx >> 6, bb = idx & 63, j = kbase + kk;
            As[kk][bb] = (j < Hh) ? hT[((long)(ti+1)*KH + j)*64 + bb] : 0.0f;
        }
        for (int idx = tid; idx < 768; idx += 192) {
            int kk = idx / 48, nn = idx % 48, j = kbase + kk, n = n0 + nn;
            Bs[kk][nn] = (j < Hh && n < Hh) ? Whp[j*Hh + n] : 0.0f;
        }
        __syncthreads();
#pragma unroll
        for (int kk = 0; kk < 16; kk++) {
            float4 av = *(const float4*)&As[kk][ty*4];
            float4 bv = *(const float4*)&Bs[kk][tx*4];
            fma16_(av, bv, acc);
        }
        __syncthreads();
    }
#pragma unroll
    for (int i = 0; i < 4; i++) {
        const int bb = ty*4 + i;
#pragma unroll
        for (int j = 0; j < 4; j++) {
            const int n = n0 + tx*4 + j;
            if (n < KOP) {
                float v = acc[i][j];
                if (n < Hh) {
                    float pb = pb_b[n];
                    for (int ks = 0; ks < 8; ks++)
                        pb += partBig[((long)ks*NBIG + NPB + n)*64 + bb];
                    v += E[(ti*Hh + n)*64 + bb] + pb;
                }
                tmpT[(ti*KOP + n)*64 + bb] = v;
            }
        }
    }
}

// Stage B: out[:, t+1, :] = tmp @ Wop + bop. grid (7, 31).
__global__ __launch_bounds__(192) void k_predb(const float* tmpT, const float* Wop,
                                               const float* bop, float* out)
{
    const int nt = blockIdx.x, ti = blockIdx.y, tid = threadIdx.x;
    const int n0 = nt*48, tx = tid % 12, ty = tid / 12;
    __shared__ float As[16][64];
    __shared__ float Bs[16][48];
    float acc[4][4] = {};
    const float* Asrc = tmpT + ti*KOP*64;

    for (int kb = 0; kb < 19; kb++) {
        const int kbase = kb*16;
        for (int idx = tid; idx < 1024; idx += 192) {
            int kk = idx >> 6, bb = idx & 63;
            As[kk][bb] = Asrc[(kbase + kk)*64 + bb];
        }
        for (int idx = tid; idx < 768; idx += 192) {
            int kk = idx / 48, nn = idx % 48, j = kbase + kk, n = n0 + nn;
            Bs[kk][nn] = (j < Hh && n < Hh) ? Wop[j*Hh + n] : 0.0f;
        }
        __syncthreads();
#pragma unroll
        for (int kk = 0; kk < 16; kk++) {
            float4 av = *(const float4*)&As[kk][ty*4];
            float4 bv = *(const float4*)&Bs[kk][tx*4];
            fma16_(av, bv, acc);
        }
        __syncthreads();
    }
#pragma unroll
    for (int i = 0; i < 4; i++) {
        const int bb = ty*4 + i;
#pragma unroll
        for (int j = 0; j < 4; j++) {
            const int n = n0 + tx*4 + j;
            if (n < Hh)
                out[(bb*Tt + (ti+1))*Hh + n] = acc[i][j] + bop[n];
        }
    }
}

// ---------------------------------------------------------------------------
extern "C" void kernel_launch(void* const* d_in, const int* in_sizes, int n_in,
                              void* d_out, int out_size, void* d_ws, size_t ws_size,
                              hipStream_t stream)
{
    const float* enc    = (const float*)d_in[0];
    const int*   caps   = (const int*)  d_in[1];
    const float* emb    = (const float*)d_in[2];
    const float* Wh0    = (const float*)d_in[3];
    const float* bh0    = (const float*)d_in[4];
    const float* Wc0    = (const float*)d_in[5];
    const float* bc0    = (const float*)d_in[6];
    const float* We_enc = (const float*)d_in[7];
    const float* We_hid = (const float*)d_in[8];
    const float* be     = (const float*)d_in[9];
    const float* Wi     = (const float*)d_in[10];
    const float* bi     = (const float*)d_in[11];
    const float* Wf     = (const float*)d_in[12];
    const float* bf     = (const float*)d_in[13];
    const float* Wo     = (const float*)d_in[14];
    const float* bo     = (const float*)d_in[15];
    const float* Wg     = (const float*)d_in[16];
    const float* bg     = (const float*)d_in[17];
    const float* Wcp    = (const float*)d_in[18];
    const float* bcp    = (const float*)d_in[19];
    const float* Whp    = (const float*)d_in[20];
    const float* bhp    = (const float*)d_in[21];
    const float* Wop    = (const float*)d_in[22];
    const float* bop    = (const float*)d_in[23];
    float* out = (float*)d_out;
    (void)We_hid; (void)be;   // softmax is invariant to the h-term: unused.

    // Workspace carve-up (floats).
    float* w = (float*)d_ws;
    float* Wbig  = w; w += 2048*NBIG;    // 4,587,520 (aliased by gpre later)
    float* W4e_p = w; w += KH*N4P;       //   369,664
    float* W4h_p = w; w += KH*N4P;       //   369,664
    float* b4p   = w; w += N4P;
    float* pb_b  = w; w += NPP;
    float* bhc   = w; w += 2*Hh;
    float* ctxT  = w; w += Ff*64;        //   131,072
    float* hT    = w; w += Tt*KH*64;     //   622,592  [t][col(304)][b]
    float* E     = w; w += 31*Hh*64;     //   595,200  [t][j][b]
    float* c0T   = w; w += KH*64;        //    19,456
    float* partBig = w; w += 8*NBIG*64;  // 1,146,880  [ks][n][b]
    float* tmpT  = w; w += 31*KOP*64;    //   603,136  [t][j][b]
    int*   flags = (int*)w; w += 128;
    // time-disjoint aliases:
    float* gpre  = Wbig;    // 31*N4P*64 = 2,412,544 <= 4,587,520 (Wbig dead after CH)
    float* meanT = tmpT;    // 131,072 (tmpT written after CH reads meanT)
    (void)ws_size; (void)in_sizes; (void)n_in; (void)out_size;

    // 1. fused init + pack + embed
    k_fused0<<<64 + NPACKWG + 2400, 256, 0, stream>>>(
        enc, We_enc, caps, emb,
        Wi, Wf, Wo, Wg, bi, bf, bo, bg, bcp, bhp, bh0, bc0, Wh0, Wc0, Wcp,
        Wbig, W4e_p, W4h_p, b4p, pb_b, bhc,
        meanT, ctxT, E, out, hT, flags);

    // 2. combined C/h0/pb GEMM
    k_gemm_CH<<<dim3(35, 8), 256, 0, stream>>>(meanT, ctxT, Wbig, partBig);

    // 3. h0 epilogue + gpre (gpre aliases Wbig -- Wbig is dead now)
    k_h0gpre<<<653, 256, 0, stream>>>(E, W4e_p, partBig, b4p, bhc, gpre, hT, c0T);

    // 4. recurrence (cooperative for co-residency; custom flag sync inside)
    {
        void* rargs[] = { (void*)&W4h_p, (void*)&gpre, (void*)&c0T,
                          (void*)&hT, (void*)&flags };
        hipLaunchCooperativeKernel((const void*)k_recs, dim3(NWG), dim3(512),
                                   rargs, 0, stream);
    }

    // 5-6. deferred prediction
    k_gemm_tmp<<<dim3(7, 31), 192, 0, stream>>>(hT, Whp, E, partBig, pb_b, tmpT);
    k_predb<<<dim3(7, 31), 192, 0, stream>>>(tmpT, Wop, bop, out);
}